// Round 5
// baseline (189.787 us; speedup 1.0000x reference)
//
#include <hip/hip_runtime.h>

// Bahdanau additive attention: B=8, TE=512, TD=256, H=256, fp32.
//   We = enc @ W_a; Uh = dec @ U_a
//   e[b,j,i] = softmax_i( sum_h V[h]*tanh(We[b,i,h]+Uh[b,j,h]) )
//   c[b,j,h] = sum_i e[b,j,i]*enc[b,i,h]
// d_out = [c (B*TD*H)] ++ [e (B*TD*TE)]
//
// Identity (R3): tanh(x) = 1 - 2/(1+exp2(Kx)), exp2(K(w+u)) = w~ * u~ with
// w~ = exp2(K*We), u~ = exp2(K*Uh) precomputed -> 1 transcendental/element.
// R4: k_attn uses 1024-thread blocks (16 waves: 2 h-halves x 8 i-ranges) for
// 32 waves/CU, and WeT stored interleaved as W4[b][h/4][i][4] so one b128
// load feeds 16 rcp + 32 fma (4x fewer vmem instructions).

#define BB 8
#define TE 512
#define TD 256
#define HH 256

#define EXP2F(x) __builtin_amdgcn_exp2f(x)
#define RCPF(x)  __builtin_amdgcn_rcpf(x)
#define KSCALE   2.8853900817779268f    // 2*log2(e)
#define NSC      (-2.8853900817779268f) // -2*log2(e)

// ---------------------------------------------------------------------------
// k_pre: C = [enc;dec] @ [Wa|Ua]; store exp2(KSCALE*C).
// Blocks 0..255: enc -> W4[b][h/4][i][4] (interleaved-transposed).
// Blocks 256..383: dec -> Uhe[row][h] (direct).
// 64x64 tile, Kc=32, 4x4 per thread (tx=h-quad, ty=i-quad).
// ---------------------------------------------------------------------------
__global__ __launch_bounds__(256) void k_pre(
    const float* __restrict__ enc, const float* __restrict__ dec,
    const float* __restrict__ Wa,  const float* __restrict__ Ua,
    float* __restrict__ W4, float* __restrict__ Uhe)
{
    const int tid = threadIdx.x;
    const bool is_enc = blockIdx.x < 256;
    const int bi = is_enc ? blockIdx.x : (blockIdx.x - 256);
    const int m0 = (bi >> 2) * 64;
    const int n0 = (bi & 3) * 64;
    const float* X = is_enc ? enc : dec;
    const float* W = is_enc ? Wa : Ua;

    __shared__ float Xs[32][68];
    __shared__ float Ws[32][68];

    const int kq = tid & 7,  xr = tid >> 3;
    const int wk = tid >> 3, wn = (tid & 7) * 8;
    const int tx = tid & 15, ty = tid >> 4;

    float acc[4][4];   // acc[r = i-offset][c = h-offset]
    #pragma unroll
    for (int r = 0; r < 4; r++)
        #pragma unroll
        for (int c = 0; c < 4; c++) acc[r][c] = 0.f;

    for (int kc = 0; kc < HH; kc += 32) {
        float4 xa = *(const float4*)(X + (size_t)(m0 + xr) * HH + kc + kq * 4);
        float4 xb = *(const float4*)(X + (size_t)(m0 + xr + 32) * HH + kc + kq * 4);
        float4 wa = *(const float4*)(W + (size_t)(kc + wk) * HH + n0 + wn);
        float4 wb = *(const float4*)(W + (size_t)(kc + wk) * HH + n0 + wn + 4);
        __syncthreads();
        Xs[kq * 4 + 0][xr] = xa.x; Xs[kq * 4 + 1][xr] = xa.y;
        Xs[kq * 4 + 2][xr] = xa.z; Xs[kq * 4 + 3][xr] = xa.w;
        Xs[kq * 4 + 0][xr + 32] = xb.x; Xs[kq * 4 + 1][xr + 32] = xb.y;
        Xs[kq * 4 + 2][xr + 32] = xb.z; Xs[kq * 4 + 3][xr + 32] = xb.w;
        *(float4*)&Ws[wk][wn]     = wa;
        *(float4*)&Ws[wk][wn + 4] = wb;
        __syncthreads();
        #pragma unroll
        for (int k = 0; k < 32; k++) {
            float4 a = *(const float4*)&Xs[k][ty * 4];   // 4 i's
            float4 b = *(const float4*)&Ws[k][tx * 4];   // 4 h's
            acc[0][0] = fmaf(a.x, b.x, acc[0][0]); acc[0][1] = fmaf(a.x, b.y, acc[0][1]);
            acc[0][2] = fmaf(a.x, b.z, acc[0][2]); acc[0][3] = fmaf(a.x, b.w, acc[0][3]);
            acc[1][0] = fmaf(a.y, b.x, acc[1][0]); acc[1][1] = fmaf(a.y, b.y, acc[1][1]);
            acc[1][2] = fmaf(a.y, b.z, acc[1][2]); acc[1][3] = fmaf(a.y, b.w, acc[1][3]);
            acc[2][0] = fmaf(a.z, b.x, acc[2][0]); acc[2][1] = fmaf(a.z, b.y, acc[2][1]);
            acc[2][2] = fmaf(a.z, b.z, acc[2][2]); acc[2][3] = fmaf(a.z, b.w, acc[2][3]);
            acc[3][0] = fmaf(a.w, b.x, acc[3][0]); acc[3][1] = fmaf(a.w, b.y, acc[3][1]);
            acc[3][2] = fmaf(a.w, b.z, acc[3][2]); acc[3][3] = fmaf(a.w, b.w, acc[3][3]);
        }
    }

    if (is_enc) {
        const int b  = m0 >> 9;                  // 512 enc rows per batch
        const int ib = (m0 & 511) + ty * 4;      // i base
        const int hq = (n0 >> 2) + tx;           // h-quad
        float* dst = W4 + (((size_t)b * 64 + hq) * TE + ib) * 4;
        #pragma unroll
        for (int r = 0; r < 4; r++) {
            float4 v;
            v.x = EXP2F(acc[r][0] * KSCALE); v.y = EXP2F(acc[r][1] * KSCALE);
            v.z = EXP2F(acc[r][2] * KSCALE); v.w = EXP2F(acc[r][3] * KSCALE);
            *(float4*)(dst + (size_t)r * 4) = v;
        }
    } else {
        #pragma unroll
        for (int r = 0; r < 4; r++) {
            float4 v;
            v.x = EXP2F(acc[r][0] * KSCALE); v.y = EXP2F(acc[r][1] * KSCALE);
            v.z = EXP2F(acc[r][2] * KSCALE); v.w = EXP2F(acc[r][3] * KSCALE);
            *(float4*)(Uhe + (size_t)(m0 + ty * 4 + r) * HH + n0 + tx * 4) = v;
        }
    }
}

// ---------------------------------------------------------------------------
// k_attn: 1024 threads = 16 waves; block owns 4 consecutive j's (same b).
// Phase A: wave w -> h-half g=w>>3 (128 h = 32 quads), i = (w&7)*64+lane.
//   Per quad: one b128 W4 load (4 h for this i) + uniform u/va s_loads;
//   16 rcp + 32 fma. Partials to sE[g], summed during softmax read.
// Softmax: waves 0-3 (wave j). Phase B: wave w -> i in [32w,32w+32), all 4 j;
//   2-round LDS reduce (waves 8-15 add into waves 0-7's partials).
// ---------------------------------------------------------------------------
__global__ __launch_bounds__(1024, 8) void k_attn(
    const float* __restrict__ enc, const float* __restrict__ W4,
    const float* __restrict__ Uhe, const float* __restrict__ Va,
    float* __restrict__ out_c, float* __restrict__ out_e)
{
    const int wv = threadIdx.x >> 6, lane = threadIdx.x & 63;
    const int b   = blockIdx.x >> 6;          // 64 blocks per batch
    const int j0  = (blockIdx.x & 63) * 4;
    const int jj0 = b * TD + j0;              // block-uniform

    __shared__ float sE[2][TE][4];   // 16 KB; sE[0] reused for probs
    __shared__ float sR[8][4][HH];   // 32 KB phase-B partials

    const int g   = wv >> 3;                  // h-half
    const int i   = ((wv & 7) << 6) + lane;   // encoder position
    const int hq0 = g * 32;

    const float* wp = W4 + (((size_t)b * 64 + hq0) * TE + i) * 4;
    const float* ua = Uhe + (size_t)jj0 * HH + hq0 * 4;   // uniform
    const float* va = Va + hq0 * 4;                        // uniform

    float a0 = 0.f, a1 = 0.f, a2 = 0.f, a3 = 0.f;
    #pragma unroll 4
    for (int q = 0; q < 32; q++) {
        float4 w4 = *(const float4*)(wp + (size_t)q * TE * 4);
        float4 v4 = *(const float4*)(va + 4 * q);
        float4 u0 = *(const float4*)(ua + 4 * q);
        float4 u1 = *(const float4*)(ua + HH + 4 * q);
        float4 u2 = *(const float4*)(ua + 2 * HH + 4 * q);
        float4 u3 = *(const float4*)(ua + 3 * HH + 4 * q);
        a0 = fmaf(v4.x, RCPF(fmaf(w4.x, u0.x, 1.f)), a0);
        a0 = fmaf(v4.y, RCPF(fmaf(w4.y, u0.y, 1.f)), a0);
        a0 = fmaf(v4.z, RCPF(fmaf(w4.z, u0.z, 1.f)), a0);
        a0 = fmaf(v4.w, RCPF(fmaf(w4.w, u0.w, 1.f)), a0);
        a1 = fmaf(v4.x, RCPF(fmaf(w4.x, u1.x, 1.f)), a1);
        a1 = fmaf(v4.y, RCPF(fmaf(w4.y, u1.y, 1.f)), a1);
        a1 = fmaf(v4.z, RCPF(fmaf(w4.z, u1.z, 1.f)), a1);
        a1 = fmaf(v4.w, RCPF(fmaf(w4.w, u1.w, 1.f)), a1);
        a2 = fmaf(v4.x, RCPF(fmaf(w4.x, u2.x, 1.f)), a2);
        a2 = fmaf(v4.y, RCPF(fmaf(w4.y, u2.y, 1.f)), a2);
        a2 = fmaf(v4.z, RCPF(fmaf(w4.z, u2.z, 1.f)), a2);
        a2 = fmaf(v4.w, RCPF(fmaf(w4.w, u2.w, 1.f)), a2);
        a3 = fmaf(v4.x, RCPF(fmaf(w4.x, u3.x, 1.f)), a3);
        a3 = fmaf(v4.y, RCPF(fmaf(w4.y, u3.y, 1.f)), a3);
        a3 = fmaf(v4.z, RCPF(fmaf(w4.z, u3.z, 1.f)), a3);
        a3 = fmaf(v4.w, RCPF(fmaf(w4.w, u3.w, 1.f)), a3);
    }
    float4 E; E.x = NSC * a0; E.y = NSC * a1; E.z = NSC * a2; E.w = NSC * a3;
    *(float4*)&sE[g][i][0] = E;     // partial energies (log2 domain)
    __syncthreads();

    // ---- softmax: wave j in 0..3 handles j0+j ----------------------------
    if (wv < 4) {
        float ev[8];
        float m = -3.0e38f;
        #pragma unroll
        for (int k = 0; k < 8; k++) {
            int ii = lane + 64 * k;
            ev[k] = sE[0][ii][wv] + sE[1][ii][wv];
            m = fmaxf(m, ev[k]);
        }
        #pragma unroll
        for (int off = 32; off; off >>= 1) m = fmaxf(m, __shfl_xor(m, off, 64));
        float s = 0.f;
        #pragma unroll
        for (int k = 0; k < 8; k++) { ev[k] = EXP2F(ev[k] - m); s += ev[k]; }
        #pragma unroll
        for (int off = 32; off; off >>= 1) s += __shfl_xor(s, off, 64);
        float rs = RCPF(s);
        float* oe = out_e + (size_t)(jj0 + wv) * TE;
        #pragma unroll
        for (int k = 0; k < 8; k++) {
            float p = ev[k] * rs;
            sE[0][lane + 64 * k][wv] = p;   // own column only; reread in B
            oe[lane + 64 * k] = p;
        }
    }
    __syncthreads();

    // ---- Phase B: wave w -> i in [32w, 32w+32), all 4 j ------------------
    const int ib = wv << 5;
    const float* eb = enc + ((size_t)b * TE + ib) * HH + 4 * lane;
    float4 c0 = {0,0,0,0}, c1 = {0,0,0,0}, c2 = {0,0,0,0}, c3 = {0,0,0,0};
    #pragma unroll 2
    for (int k = 0; k < 32; k++) {
        float4 p = *(const float4*)&sE[0][ib + k][0];  // broadcast
        float4 q = *(const float4*)(eb + (size_t)k * HH);
        c0.x = fmaf(p.x, q.x, c0.x); c0.y = fmaf(p.x, q.y, c0.y);
        c0.z = fmaf(p.x, q.z, c0.z); c0.w = fmaf(p.x, q.w, c0.w);
        c1.x = fmaf(p.y, q.x, c1.x); c1.y = fmaf(p.y, q.y, c1.y);
        c1.z = fmaf(p.y, q.z, c1.z); c1.w = fmaf(p.y, q.w, c1.w);
        c2.x = fmaf(p.z, q.x, c2.x); c2.y = fmaf(p.z, q.y, c2.y);
        c2.z = fmaf(p.z, q.z, c2.z); c2.w = fmaf(p.z, q.w, c2.w);
        c3.x = fmaf(p.w, q.x, c3.x); c3.y = fmaf(p.w, q.y, c3.y);
        c3.z = fmaf(p.w, q.z, c3.z); c3.w = fmaf(p.w, q.w, c3.w);
    }
    if (wv < 8) {
        *(float4*)&sR[wv][0][4 * lane] = c0;
        *(float4*)&sR[wv][1][4 * lane] = c1;
        *(float4*)&sR[wv][2][4 * lane] = c2;
        *(float4*)&sR[wv][3][4 * lane] = c3;
    }
    __syncthreads();
    if (wv >= 8) {
        const int w8 = wv - 8;
        float4 t;
        t = *(const float4*)&sR[w8][0][4 * lane];
        t.x += c0.x; t.y += c0.y; t.z += c0.z; t.w += c0.w;
        *(float4*)&sR[w8][0][4 * lane] = t;
        t = *(const float4*)&sR[w8][1][4 * lane];
        t.x += c1.x; t.y += c1.y; t.z += c1.z; t.w += c1.w;
        *(float4*)&sR[w8][1][4 * lane] = t;
        t = *(const float4*)&sR[w8][2][4 * lane];
        t.x += c2.x; t.y += c2.y; t.z += c2.z; t.w += c2.w;
        *(float4*)&sR[w8][2][4 * lane] = t;
        t = *(const float4*)&sR[w8][3][4 * lane];
        t.x += c3.x; t.y += c3.y; t.z += c3.z; t.w += c3.w;
        *(float4*)&sR[w8][3][4 * lane] = t;
    }
    __syncthreads();
    if (wv < 8) {
        const int jr = wv & 3;
        const int h2 = (wv >> 2) * 128 + 2 * lane;
        float sx = 0.f, sy = 0.f;
        #pragma unroll
        for (int ww = 0; ww < 8; ww++) {
            float2 t = *(const float2*)&sR[ww][jr][h2];
            sx += t.x; sy += t.y;
        }
        float2 o; o.x = sx; o.y = sy;
        *(float2*)(out_c + (size_t)(jj0 + jr) * HH + h2) = o;
    }
}

extern "C" void kernel_launch(void* const* d_in, const int* in_sizes, int n_in,
                              void* d_out, int out_size, void* d_ws, size_t ws_size,
                              hipStream_t stream) {
    const float* enc = (const float*)d_in[0];
    const float* dec = (const float*)d_in[1];
    const float* Wa  = (const float*)d_in[2];
    const float* Ua  = (const float*)d_in[3];
    const float* Va  = (const float*)d_in[4];

    float* W4  = (float*)d_ws;                       // exp2-domain, interleaved
    float* Uhe = W4 + (size_t)BB * HH * TE;          // exp2-domain, B*TD*H

    float* out_c = (float*)d_out;                    // [B,TD,H]
    float* out_e = out_c + (size_t)BB * TD * HH;     // [B,TD,TE]

    k_pre<<<384, 256, 0, stream>>>(enc, dec, Wa, Ua, W4, Uhe);
    k_attn<<<BB * TD / 4, 1024, 0, stream>>>(enc, W4, Uhe, Va, out_c, out_e);
}

// Round 6
// 126.179 us; speedup vs baseline: 1.5041x; 1.5041x over previous
//
#include <hip/hip_runtime.h>

// Bahdanau additive attention: B=8, TE=512, TD=256, H=256, fp32.
//   We = enc @ W_a; Uh = dec @ U_a
//   e[b,j,i] = softmax_i( sum_h V[h]*tanh(We[b,i,h]+Uh[b,j,h]) )
//   c[b,j,h] = sum_i e[b,j,i]*enc[b,i,h]
// d_out = [c (B*TD*H)] ++ [e (B*TD*TE)]
//
// Identity (R3): tanh(x) = 1 - 2/(1+exp2(Kx)); exp2(K(w+u)) = w~*u~ with
// w~, u~ precomputed in exp2 domain -> 1 transcendental per element.
// R6: 512-thread blocks (no (1024,8) launch-bounds spill trap — R5 spilled
// ~280 MB of scratch), grid 1024 (block owns 2 j's) -> 4 blocks/CU, 32
// waves/CU capacity with only ~24 live VGPRs in phase A. W4 interleaved
// layout kept: one b128 load feeds 4h x 2j = 8 rcp + 16 fma.

#define BB 8
#define TE 512
#define TD 256
#define HH 256

#define EXP2F(x) __builtin_amdgcn_exp2f(x)
#define RCPF(x)  __builtin_amdgcn_rcpf(x)
#define KSCALE   2.8853900817779268f    // 2*log2(e)
#define NSC      (-2.8853900817779268f) // -2*log2(e)

// ---------------------------------------------------------------------------
// k_pre: C = [enc;dec] @ [Wa|Ua]; store exp2(KSCALE*C).
// Blocks 0..255: enc -> W4[b][h/4][i][4] (interleaved-transposed).
// Blocks 256..383: dec -> Uhe[row][h] (direct).
// 64x64 tile, Kc=32, 4x4 per thread (tx=h-quad, ty=i-quad).
// ---------------------------------------------------------------------------
__global__ __launch_bounds__(256) void k_pre(
    const float* __restrict__ enc, const float* __restrict__ dec,
    const float* __restrict__ Wa,  const float* __restrict__ Ua,
    float* __restrict__ W4, float* __restrict__ Uhe)
{
    const int tid = threadIdx.x;
    const bool is_enc = blockIdx.x < 256;
    const int bi = is_enc ? blockIdx.x : (blockIdx.x - 256);
    const int m0 = (bi >> 2) * 64;
    const int n0 = (bi & 3) * 64;
    const float* X = is_enc ? enc : dec;
    const float* W = is_enc ? Wa : Ua;

    __shared__ float Xs[32][68];
    __shared__ float Ws[32][68];

    const int kq = tid & 7,  xr = tid >> 3;
    const int wk = tid >> 3, wn = (tid & 7) * 8;
    const int tx = tid & 15, ty = tid >> 4;

    float acc[4][4];   // acc[r = i-offset][c = h-offset]
    #pragma unroll
    for (int r = 0; r < 4; r++)
        #pragma unroll
        for (int c = 0; c < 4; c++) acc[r][c] = 0.f;

    for (int kc = 0; kc < HH; kc += 32) {
        float4 xa = *(const float4*)(X + (size_t)(m0 + xr) * HH + kc + kq * 4);
        float4 xb = *(const float4*)(X + (size_t)(m0 + xr + 32) * HH + kc + kq * 4);
        float4 wa = *(const float4*)(W + (size_t)(kc + wk) * HH + n0 + wn);
        float4 wb = *(const float4*)(W + (size_t)(kc + wk) * HH + n0 + wn + 4);
        __syncthreads();
        Xs[kq * 4 + 0][xr] = xa.x; Xs[kq * 4 + 1][xr] = xa.y;
        Xs[kq * 4 + 2][xr] = xa.z; Xs[kq * 4 + 3][xr] = xa.w;
        Xs[kq * 4 + 0][xr + 32] = xb.x; Xs[kq * 4 + 1][xr + 32] = xb.y;
        Xs[kq * 4 + 2][xr + 32] = xb.z; Xs[kq * 4 + 3][xr + 32] = xb.w;
        *(float4*)&Ws[wk][wn]     = wa;
        *(float4*)&Ws[wk][wn + 4] = wb;
        __syncthreads();
        #pragma unroll
        for (int k = 0; k < 32; k++) {
            float4 a = *(const float4*)&Xs[k][ty * 4];   // 4 i's
            float4 b = *(const float4*)&Ws[k][tx * 4];   // 4 h's
            acc[0][0] = fmaf(a.x, b.x, acc[0][0]); acc[0][1] = fmaf(a.x, b.y, acc[0][1]);
            acc[0][2] = fmaf(a.x, b.z, acc[0][2]); acc[0][3] = fmaf(a.x, b.w, acc[0][3]);
            acc[1][0] = fmaf(a.y, b.x, acc[1][0]); acc[1][1] = fmaf(a.y, b.y, acc[1][1]);
            acc[1][2] = fmaf(a.y, b.z, acc[1][2]); acc[1][3] = fmaf(a.y, b.w, acc[1][3]);
            acc[2][0] = fmaf(a.z, b.x, acc[2][0]); acc[2][1] = fmaf(a.z, b.y, acc[2][1]);
            acc[2][2] = fmaf(a.z, b.z, acc[2][2]); acc[2][3] = fmaf(a.z, b.w, acc[2][3]);
            acc[3][0] = fmaf(a.w, b.x, acc[3][0]); acc[3][1] = fmaf(a.w, b.y, acc[3][1]);
            acc[3][2] = fmaf(a.w, b.z, acc[3][2]); acc[3][3] = fmaf(a.w, b.w, acc[3][3]);
        }
    }

    if (is_enc) {
        const int b  = m0 >> 9;                  // 512 enc rows per batch
        const int ib = (m0 & 511) + ty * 4;      // i base
        const int hq = (n0 >> 2) + tx;           // h-quad
        float* dst = W4 + (((size_t)b * 64 + hq) * TE + ib) * 4;
        #pragma unroll
        for (int r = 0; r < 4; r++) {
            float4 v;
            v.x = EXP2F(acc[r][0] * KSCALE); v.y = EXP2F(acc[r][1] * KSCALE);
            v.z = EXP2F(acc[r][2] * KSCALE); v.w = EXP2F(acc[r][3] * KSCALE);
            *(float4*)(dst + (size_t)r * 4) = v;
        }
    } else {
        #pragma unroll
        for (int r = 0; r < 4; r++) {
            float4 v;
            v.x = EXP2F(acc[r][0] * KSCALE); v.y = EXP2F(acc[r][1] * KSCALE);
            v.z = EXP2F(acc[r][2] * KSCALE); v.w = EXP2F(acc[r][3] * KSCALE);
            *(float4*)(Uhe + (size_t)(m0 + ty * 4 + r) * HH + n0 + tx * 4) = v;
        }
    }
}

// ---------------------------------------------------------------------------
// k_attn: 512 threads = 8 waves; block owns 2 consecutive j's (same b).
// Phase A: wave w -> i = 64w+lane, all 256 h (64 quads); per quad one b128
//   W4 load + uniform u/va loads -> 8 rcp + 16 fma; 2 accumulators.
// Softmax: waves 0-1 (wave = j). Phase B: wave w -> i in [64w,64w+64),
//   both j; partials reduced via LDS.
// ---------------------------------------------------------------------------
__global__ __launch_bounds__(512) void k_attn(
    const float* __restrict__ enc, const float* __restrict__ W4,
    const float* __restrict__ Uhe, const float* __restrict__ Va,
    float* __restrict__ out_c, float* __restrict__ out_e)
{
    const int wv = threadIdx.x >> 6, lane = threadIdx.x & 63;
    const int b   = blockIdx.x >> 7;          // 128 blocks per batch
    const int j0  = (blockIdx.x & 127) * 2;
    const int jj0 = b * TD + j0;              // block-uniform

    __shared__ float sP[TE][2];      // 4 KB: energies -> probabilities
    __shared__ float sR[8][2][HH];   // 16 KB: phase-B partials

    const int i = (wv << 6) + lane;
    const float* wp = W4 + ((size_t)b * 64 * TE + i) * 4;
    const float* ua = Uhe + (size_t)jj0 * HH;   // block-uniform
    const float* va = Va;                        // uniform

    float a0 = 0.f, a1 = 0.f;
    #pragma unroll 2
    for (int q = 0; q < 64; q++) {
        float4 w4 = *(const float4*)(wp + (size_t)q * TE * 4);
        float4 v4 = *(const float4*)(va + 4 * q);
        float4 u0 = *(const float4*)(ua + 4 * q);
        float4 u1 = *(const float4*)(ua + HH + 4 * q);
        a0 = fmaf(v4.x, RCPF(fmaf(w4.x, u0.x, 1.f)), a0);
        a0 = fmaf(v4.y, RCPF(fmaf(w4.y, u0.y, 1.f)), a0);
        a0 = fmaf(v4.z, RCPF(fmaf(w4.z, u0.z, 1.f)), a0);
        a0 = fmaf(v4.w, RCPF(fmaf(w4.w, u0.w, 1.f)), a0);
        a1 = fmaf(v4.x, RCPF(fmaf(w4.x, u1.x, 1.f)), a1);
        a1 = fmaf(v4.y, RCPF(fmaf(w4.y, u1.y, 1.f)), a1);
        a1 = fmaf(v4.z, RCPF(fmaf(w4.z, u1.z, 1.f)), a1);
        a1 = fmaf(v4.w, RCPF(fmaf(w4.w, u1.w, 1.f)), a1);
    }
    float2 E; E.x = NSC * a0; E.y = NSC * a1;
    *(float2*)&sP[i][0] = E;
    __syncthreads();

    // ---- softmax: wave 0 -> j0, wave 1 -> j0+1 ---------------------------
    if (wv < 2) {
        float ev[8];
        float m = -3.0e38f;
        #pragma unroll
        for (int k = 0; k < 8; k++) {
            ev[k] = sP[lane + 64 * k][wv];
            m = fmaxf(m, ev[k]);
        }
        #pragma unroll
        for (int off = 32; off; off >>= 1) m = fmaxf(m, __shfl_xor(m, off, 64));
        float s = 0.f;
        #pragma unroll
        for (int k = 0; k < 8; k++) { ev[k] = EXP2F(ev[k] - m); s += ev[k]; }
        #pragma unroll
        for (int off = 32; off; off >>= 1) s += __shfl_xor(s, off, 64);
        float rs = RCPF(s);
        float* oe = out_e + (size_t)(jj0 + wv) * TE;
        #pragma unroll
        for (int k = 0; k < 8; k++) {
            float p = ev[k] * rs;
            sP[lane + 64 * k][wv] = p;
            oe[lane + 64 * k] = p;
        }
    }
    __syncthreads();

    // ---- Phase B: wave w -> i in [64w, 64w+64), both j -------------------
    const int ib = wv << 6;
    const float* eb = enc + ((size_t)b * TE + ib) * HH + 4 * lane;
    float4 c0 = {0,0,0,0}, c1 = {0,0,0,0};
    #pragma unroll 2
    for (int k = 0; k < 64; k++) {
        float2 p = *(const float2*)&sP[ib + k][0];     // broadcast
        float4 q = *(const float4*)(eb + (size_t)k * HH);
        c0.x = fmaf(p.x, q.x, c0.x); c0.y = fmaf(p.x, q.y, c0.y);
        c0.z = fmaf(p.x, q.z, c0.z); c0.w = fmaf(p.x, q.w, c0.w);
        c1.x = fmaf(p.y, q.x, c1.x); c1.y = fmaf(p.y, q.y, c1.y);
        c1.z = fmaf(p.y, q.z, c1.z); c1.w = fmaf(p.y, q.w, c1.w);
    }
    *(float4*)&sR[wv][0][4 * lane] = c0;
    *(float4*)&sR[wv][1][4 * lane] = c1;
    __syncthreads();

    // ---- final reduce: wave w -> (j = w&1, h-quarter = w>>1) -------------
    {
        const int jr = wv & 1;
        const int h  = (wv >> 1) * 64 + lane;
        float s = 0.f;
        #pragma unroll
        for (int ww = 0; ww < 8; ww++) s += sR[ww][jr][h];
        out_c[(size_t)(jj0 + jr) * HH + h] = s;
    }
}

extern "C" void kernel_launch(void* const* d_in, const int* in_sizes, int n_in,
                              void* d_out, int out_size, void* d_ws, size_t ws_size,
                              hipStream_t stream) {
    const float* enc = (const float*)d_in[0];
    const float* dec = (const float*)d_in[1];
    const float* Wa  = (const float*)d_in[2];
    const float* Ua  = (const float*)d_in[3];
    const float* Va  = (const float*)d_in[4];

    float* W4  = (float*)d_ws;                       // exp2-domain, interleaved
    float* Uhe = W4 + (size_t)BB * HH * TE;          // exp2-domain, B*TD*H

    float* out_c = (float*)d_out;                    // [B,TD,H]
    float* out_e = out_c + (size_t)BB * TD * HH;     // [B,TD,TE]

    k_pre<<<384, 256, 0, stream>>>(enc, dec, Wa, Ua, W4, Uhe);
    k_attn<<<BB * TD / 2, 512, 0, stream>>>(enc, W4, Uhe, Va, out_c, out_e);
}

// Round 7
// 120.025 us; speedup vs baseline: 1.5812x; 1.0513x over previous
//
#include <hip/hip_runtime.h>

// Bahdanau additive attention: B=8, TE=512, TD=256, H=256, fp32.
//   We = enc @ W_a; Uh = dec @ U_a
//   e[b,j,i] = softmax_i( sum_h V[h]*tanh(We[b,i,h]+Uh[b,j,h]) )
//   c[b,j,h] = sum_i e[b,j,i]*enc[b,i,h]
// d_out = [c (B*TD*H)] ++ [e (B*TD*TE)]
//
// Identity (R3): tanh(x) = 1 - 2/(1+exp2(Kx)); exp2(K(w+u)) = w~*u~ in the
// exp2 domain -> 1 transcendental (v_rcp) per element.
// R7: XCD-aware swizzle (b = blockIdx&7: one batch per XCD, working set
// fits that XCD's 4MB L2) + 4 j's per 512-thread block (halves die-level
// traffic vs R6). R5 lesson: no (1024,8) launch bounds — spills.

#define BB 8
#define TE 512
#define TD 256
#define HH 256

#define EXP2F(x) __builtin_amdgcn_exp2f(x)
#define RCPF(x)  __builtin_amdgcn_rcpf(x)
#define KSCALE   2.8853900817779268f    // 2*log2(e)
#define NSC      (-2.8853900817779268f) // -2*log2(e)

// ---------------------------------------------------------------------------
// k_pre: C = [enc;dec] @ [Wa|Ua]; store exp2(KSCALE*C).
// Blocks 0..255: enc -> W4[b][h/4][i][4] (interleaved-transposed).
// Blocks 256..383: dec -> Uhe[row][h] (direct).
// 64x64 tile, Kc=32, 4x4 per thread (tx=h-quad, ty=i-quad).
// ---------------------------------------------------------------------------
__global__ __launch_bounds__(256) void k_pre(
    const float* __restrict__ enc, const float* __restrict__ dec,
    const float* __restrict__ Wa,  const float* __restrict__ Ua,
    float* __restrict__ W4, float* __restrict__ Uhe)
{
    const int tid = threadIdx.x;
    const bool is_enc = blockIdx.x < 256;
    const int bi = is_enc ? blockIdx.x : (blockIdx.x - 256);
    const int m0 = (bi >> 2) * 64;
    const int n0 = (bi & 3) * 64;
    const float* X = is_enc ? enc : dec;
    const float* W = is_enc ? Wa : Ua;

    __shared__ float Xs[32][68];
    __shared__ float Ws[32][68];

    const int kq = tid & 7,  xr = tid >> 3;
    const int wk = tid >> 3, wn = (tid & 7) * 8;
    const int tx = tid & 15, ty = tid >> 4;

    float acc[4][4];   // acc[r = i-offset][c = h-offset]
    #pragma unroll
    for (int r = 0; r < 4; r++)
        #pragma unroll
        for (int c = 0; c < 4; c++) acc[r][c] = 0.f;

    for (int kc = 0; kc < HH; kc += 32) {
        float4 xa = *(const float4*)(X + (size_t)(m0 + xr) * HH + kc + kq * 4);
        float4 xb = *(const float4*)(X + (size_t)(m0 + xr + 32) * HH + kc + kq * 4);
        float4 wa = *(const float4*)(W + (size_t)(kc + wk) * HH + n0 + wn);
        float4 wb = *(const float4*)(W + (size_t)(kc + wk) * HH + n0 + wn + 4);
        __syncthreads();
        Xs[kq * 4 + 0][xr] = xa.x; Xs[kq * 4 + 1][xr] = xa.y;
        Xs[kq * 4 + 2][xr] = xa.z; Xs[kq * 4 + 3][xr] = xa.w;
        Xs[kq * 4 + 0][xr + 32] = xb.x; Xs[kq * 4 + 1][xr + 32] = xb.y;
        Xs[kq * 4 + 2][xr + 32] = xb.z; Xs[kq * 4 + 3][xr + 32] = xb.w;
        *(float4*)&Ws[wk][wn]     = wa;
        *(float4*)&Ws[wk][wn + 4] = wb;
        __syncthreads();
        #pragma unroll
        for (int k = 0; k < 32; k++) {
            float4 a = *(const float4*)&Xs[k][ty * 4];   // 4 i's
            float4 b = *(const float4*)&Ws[k][tx * 4];   // 4 h's
            acc[0][0] = fmaf(a.x, b.x, acc[0][0]); acc[0][1] = fmaf(a.x, b.y, acc[0][1]);
            acc[0][2] = fmaf(a.x, b.z, acc[0][2]); acc[0][3] = fmaf(a.x, b.w, acc[0][3]);
            acc[1][0] = fmaf(a.y, b.x, acc[1][0]); acc[1][1] = fmaf(a.y, b.y, acc[1][1]);
            acc[1][2] = fmaf(a.y, b.z, acc[1][2]); acc[1][3] = fmaf(a.y, b.w, acc[1][3]);
            acc[2][0] = fmaf(a.z, b.x, acc[2][0]); acc[2][1] = fmaf(a.z, b.y, acc[2][1]);
            acc[2][2] = fmaf(a.z, b.z, acc[2][2]); acc[2][3] = fmaf(a.z, b.w, acc[2][3]);
            acc[3][0] = fmaf(a.w, b.x, acc[3][0]); acc[3][1] = fmaf(a.w, b.y, acc[3][1]);
            acc[3][2] = fmaf(a.w, b.z, acc[3][2]); acc[3][3] = fmaf(a.w, b.w, acc[3][3]);
        }
    }

    if (is_enc) {
        const int b  = m0 >> 9;                  // 512 enc rows per batch
        const int ib = (m0 & 511) + ty * 4;      // i base
        const int hq = (n0 >> 2) + tx;           // h-quad
        float* dst = W4 + (((size_t)b * 64 + hq) * TE + ib) * 4;
        #pragma unroll
        for (int r = 0; r < 4; r++) {
            float4 v;
            v.x = EXP2F(acc[r][0] * KSCALE); v.y = EXP2F(acc[r][1] * KSCALE);
            v.z = EXP2F(acc[r][2] * KSCALE); v.w = EXP2F(acc[r][3] * KSCALE);
            *(float4*)(dst + (size_t)r * 4) = v;
        }
    } else {
        #pragma unroll
        for (int r = 0; r < 4; r++) {
            float4 v;
            v.x = EXP2F(acc[r][0] * KSCALE); v.y = EXP2F(acc[r][1] * KSCALE);
            v.z = EXP2F(acc[r][2] * KSCALE); v.w = EXP2F(acc[r][3] * KSCALE);
            *(float4*)(Uhe + (size_t)(m0 + ty * 4 + r) * HH + n0 + tx * 4) = v;
        }
    }
}

// ---------------------------------------------------------------------------
// k_attn: 512 threads = 8 waves; block owns 4 consecutive j's of ONE batch,
// batch chosen by blockIdx&7 (XCD-local: all of batch b's blocks on XCD b).
// Phase A: wave w -> i = 64w+lane, all 256 h (64 quads); per quad one b128
//   W4 load + uniform u (4 rows) / va loads -> 16 rcp + 32 fma, 4 acc chains.
// Softmax: waves 0-3 (wave = j). Phase B: wave w -> i in [64w,64w+64),
//   all 4 j; partials via 32 KB LDS reduce.
// ---------------------------------------------------------------------------
__global__ __launch_bounds__(512) void k_attn(
    const float* __restrict__ enc, const float* __restrict__ W4,
    const float* __restrict__ Uhe, const float* __restrict__ Va,
    float* __restrict__ out_c, float* __restrict__ out_e)
{
    const int wv = threadIdx.x >> 6, lane = threadIdx.x & 63;
    const int b   = blockIdx.x & 7;           // XCD-local batch
    const int j0  = (blockIdx.x >> 3) * 4;    // 64 j-groups per batch
    const int jj0 = b * TD + j0;              // block-uniform

    __shared__ float sP[4][TE];      // 8 KB: energies -> probabilities
    __shared__ float sR[8][4][HH];   // 32 KB: phase-B partials

    const int i = (wv << 6) + lane;
    const float* wp = W4 + ((size_t)b * 64 * TE + i) * 4;
    const float* ua = Uhe + (size_t)jj0 * HH;   // block-uniform -> s_load
    const float* va = Va;                        // uniform

    float a0 = 0.f, a1 = 0.f, a2 = 0.f, a3 = 0.f;
    #pragma unroll 2
    for (int q = 0; q < 64; q++) {
        float4 w4 = *(const float4*)(wp + (size_t)q * TE * 4);
        float4 v4 = *(const float4*)(va + 4 * q);
        float4 u0 = *(const float4*)(ua + 4 * q);
        float4 u1 = *(const float4*)(ua + HH + 4 * q);
        float4 u2 = *(const float4*)(ua + 2 * HH + 4 * q);
        float4 u3 = *(const float4*)(ua + 3 * HH + 4 * q);
        a0 = fmaf(v4.x, RCPF(fmaf(w4.x, u0.x, 1.f)), a0);
        a0 = fmaf(v4.y, RCPF(fmaf(w4.y, u0.y, 1.f)), a0);
        a0 = fmaf(v4.z, RCPF(fmaf(w4.z, u0.z, 1.f)), a0);
        a0 = fmaf(v4.w, RCPF(fmaf(w4.w, u0.w, 1.f)), a0);
        a1 = fmaf(v4.x, RCPF(fmaf(w4.x, u1.x, 1.f)), a1);
        a1 = fmaf(v4.y, RCPF(fmaf(w4.y, u1.y, 1.f)), a1);
        a1 = fmaf(v4.z, RCPF(fmaf(w4.z, u1.z, 1.f)), a1);
        a1 = fmaf(v4.w, RCPF(fmaf(w4.w, u1.w, 1.f)), a1);
        a2 = fmaf(v4.x, RCPF(fmaf(w4.x, u2.x, 1.f)), a2);
        a2 = fmaf(v4.y, RCPF(fmaf(w4.y, u2.y, 1.f)), a2);
        a2 = fmaf(v4.z, RCPF(fmaf(w4.z, u2.z, 1.f)), a2);
        a2 = fmaf(v4.w, RCPF(fmaf(w4.w, u2.w, 1.f)), a2);
        a3 = fmaf(v4.x, RCPF(fmaf(w4.x, u3.x, 1.f)), a3);
        a3 = fmaf(v4.y, RCPF(fmaf(w4.y, u3.y, 1.f)), a3);
        a3 = fmaf(v4.z, RCPF(fmaf(w4.z, u3.z, 1.f)), a3);
        a3 = fmaf(v4.w, RCPF(fmaf(w4.w, u3.w, 1.f)), a3);
    }
    // conflict-free b32 writes (lane-stride 4B), energies in log2 domain
    sP[0][i] = NSC * a0;
    sP[1][i] = NSC * a1;
    sP[2][i] = NSC * a2;
    sP[3][i] = NSC * a3;
    __syncthreads();

    // ---- softmax: wave w in 0..3 handles j0+w ----------------------------
    if (wv < 4) {
        float ev[8];
        float m = -3.0e38f;
        #pragma unroll
        for (int k = 0; k < 8; k++) {
            ev[k] = sP[wv][lane + 64 * k];
            m = fmaxf(m, ev[k]);
        }
        #pragma unroll
        for (int off = 32; off; off >>= 1) m = fmaxf(m, __shfl_xor(m, off, 64));
        float s = 0.f;
        #pragma unroll
        for (int k = 0; k < 8; k++) { ev[k] = EXP2F(ev[k] - m); s += ev[k]; }
        #pragma unroll
        for (int off = 32; off; off >>= 1) s += __shfl_xor(s, off, 64);
        float rs = RCPF(s);
        float* oe = out_e + (size_t)(jj0 + wv) * TE;
        #pragma unroll
        for (int k = 0; k < 8; k++) {
            float p = ev[k] * rs;
            sP[wv][lane + 64 * k] = p;
            oe[lane + 64 * k] = p;
        }
    }
    __syncthreads();

    // ---- Phase B: wave w -> i in [64w, 64w+64), all 4 j ------------------
    const int ib = wv << 6;
    const float* eb = enc + ((size_t)b * TE + ib) * HH + 4 * lane;
    float4 c0 = {0,0,0,0}, c1 = {0,0,0,0}, c2 = {0,0,0,0}, c3 = {0,0,0,0};
    #pragma unroll 2
    for (int k = 0; k < 64; k++) {
        float p0 = sP[0][ib + k];   // uniform broadcasts
        float p1 = sP[1][ib + k];
        float p2 = sP[2][ib + k];
        float p3 = sP[3][ib + k];
        float4 q = *(const float4*)(eb + (size_t)k * HH);
        c0.x = fmaf(p0, q.x, c0.x); c0.y = fmaf(p0, q.y, c0.y);
        c0.z = fmaf(p0, q.z, c0.z); c0.w = fmaf(p0, q.w, c0.w);
        c1.x = fmaf(p1, q.x, c1.x); c1.y = fmaf(p1, q.y, c1.y);
        c1.z = fmaf(p1, q.z, c1.z); c1.w = fmaf(p1, q.w, c1.w);
        c2.x = fmaf(p2, q.x, c2.x); c2.y = fmaf(p2, q.y, c2.y);
        c2.z = fmaf(p2, q.z, c2.z); c2.w = fmaf(p2, q.w, c2.w);
        c3.x = fmaf(p3, q.x, c3.x); c3.y = fmaf(p3, q.y, c3.y);
        c3.z = fmaf(p3, q.z, c3.z); c3.w = fmaf(p3, q.w, c3.w);
    }
    *(float4*)&sR[wv][0][4 * lane] = c0;
    *(float4*)&sR[wv][1][4 * lane] = c1;
    *(float4*)&sR[wv][2][4 * lane] = c2;
    *(float4*)&sR[wv][3][4 * lane] = c3;
    __syncthreads();

    // ---- final reduce: wave w -> (j = w&3, h-half = w>>2) ----------------
    {
        const int jr = wv & 3;
        const int h2 = (wv >> 2) * 128 + 2 * lane;
        float sx = 0.f, sy = 0.f;
        #pragma unroll
        for (int ww = 0; ww < 8; ww++) {
            float2 t = *(const float2*)&sR[ww][jr][h2];
            sx += t.x; sy += t.y;
        }
        float2 o; o.x = sx; o.y = sy;
        *(float2*)(out_c + (size_t)(jj0 + jr) * HH + h2) = o;
    }
}

extern "C" void kernel_launch(void* const* d_in, const int* in_sizes, int n_in,
                              void* d_out, int out_size, void* d_ws, size_t ws_size,
                              hipStream_t stream) {
    const float* enc = (const float*)d_in[0];
    const float* dec = (const float*)d_in[1];
    const float* Wa  = (const float*)d_in[2];
    const float* Ua  = (const float*)d_in[3];
    const float* Va  = (const float*)d_in[4];

    float* W4  = (float*)d_ws;                       // exp2-domain, interleaved
    float* Uhe = W4 + (size_t)BB * HH * TE;          // exp2-domain, B*TD*H

    float* out_c = (float*)d_out;                    // [B,TD,H]
    float* out_e = out_c + (size_t)BB * TD * HH;     // [B,TD,TE]

    k_pre<<<384, 256, 0, stream>>>(enc, dec, Wa, Ua, W4, Uhe);
    k_attn<<<BB * TD / 4, 512, 0, stream>>>(enc, W4, Uhe, Va, out_c, out_e);
}

// Round 8
// 113.604 us; speedup vs baseline: 1.6706x; 1.0565x over previous
//
#include <hip/hip_runtime.h>

// Bahdanau additive attention: B=8, TE=512, TD=256, H=256, fp32.
//   We = enc @ W_a; Uh = dec @ U_a
//   e[b,j,i] = softmax_i( sum_h V[h]*tanh(We[b,i,h]+Uh[b,j,h]) )
//   c[b,j,h] = sum_i e[b,j,i]*enc[b,i,h]
// d_out = [c (B*TD*H)] ++ [e (B*TD*TE)]
//
// Identity (R3): tanh(x) = 1 - 2/(1+exp2(Kx)); exp2(K(w+u)) = w~*u~ in the
// exp2 domain -> v_rcp is the only transcendental.
// R8: 4-way reciprocal batching — sum_{k=1..4} v_k/A_k = num/(ABCD) with
// num,den built from 14 full-rate ops + ONE rcp per 4 elements (was 8+4).
// Range: A in [1, 1+2^~12], den <= ~2^48 — no overflow; rcp err ~1e-7.
// R7 keeps: XCD swizzle (b = blockIdx&7), 4 j/block, interleaved W4 layout.
// R5 lesson: no (1024,8) launch bounds — spills.

#define BB 8
#define TE 512
#define TD 256
#define HH 256

#define EXP2F(x) __builtin_amdgcn_exp2f(x)
#define RCPF(x)  __builtin_amdgcn_rcpf(x)
#define KSCALE   2.8853900817779268f    // 2*log2(e)
#define NSC      (-2.8853900817779268f) // -2*log2(e)

// ---------------------------------------------------------------------------
// k_pre: C = [enc;dec] @ [Wa|Ua]; store exp2(KSCALE*C).
// Blocks 0..255: enc -> W4[b][h/4][i][4] (interleaved-transposed).
// Blocks 256..383: dec -> Uhe[row][h] (direct).
// 64x64 tile, Kc=32, 4x4 per thread (tx=h-quad, ty=i-quad).
// ---------------------------------------------------------------------------
__global__ __launch_bounds__(256) void k_pre(
    const float* __restrict__ enc, const float* __restrict__ dec,
    const float* __restrict__ Wa,  const float* __restrict__ Ua,
    float* __restrict__ W4, float* __restrict__ Uhe)
{
    const int tid = threadIdx.x;
    const bool is_enc = blockIdx.x < 256;
    const int bi = is_enc ? blockIdx.x : (blockIdx.x - 256);
    const int m0 = (bi >> 2) * 64;
    const int n0 = (bi & 3) * 64;
    const float* X = is_enc ? enc : dec;
    const float* W = is_enc ? Wa : Ua;

    __shared__ float Xs[32][68];
    __shared__ float Ws[32][68];

    const int kq = tid & 7,  xr = tid >> 3;
    const int wk = tid >> 3, wn = (tid & 7) * 8;
    const int tx = tid & 15, ty = tid >> 4;

    float acc[4][4];   // acc[r = i-offset][c = h-offset]
    #pragma unroll
    for (int r = 0; r < 4; r++)
        #pragma unroll
        for (int c = 0; c < 4; c++) acc[r][c] = 0.f;

    for (int kc = 0; kc < HH; kc += 32) {
        float4 xa = *(const float4*)(X + (size_t)(m0 + xr) * HH + kc + kq * 4);
        float4 xb = *(const float4*)(X + (size_t)(m0 + xr + 32) * HH + kc + kq * 4);
        float4 wa = *(const float4*)(W + (size_t)(kc + wk) * HH + n0 + wn);
        float4 wb = *(const float4*)(W + (size_t)(kc + wk) * HH + n0 + wn + 4);
        __syncthreads();
        Xs[kq * 4 + 0][xr] = xa.x; Xs[kq * 4 + 1][xr] = xa.y;
        Xs[kq * 4 + 2][xr] = xa.z; Xs[kq * 4 + 3][xr] = xa.w;
        Xs[kq * 4 + 0][xr + 32] = xb.x; Xs[kq * 4 + 1][xr + 32] = xb.y;
        Xs[kq * 4 + 2][xr + 32] = xb.z; Xs[kq * 4 + 3][xr + 32] = xb.w;
        *(float4*)&Ws[wk][wn]     = wa;
        *(float4*)&Ws[wk][wn + 4] = wb;
        __syncthreads();
        #pragma unroll
        for (int k = 0; k < 32; k++) {
            float4 a = *(const float4*)&Xs[k][ty * 4];   // 4 i's
            float4 b = *(const float4*)&Ws[k][tx * 4];   // 4 h's
            acc[0][0] = fmaf(a.x, b.x, acc[0][0]); acc[0][1] = fmaf(a.x, b.y, acc[0][1]);
            acc[0][2] = fmaf(a.x, b.z, acc[0][2]); acc[0][3] = fmaf(a.x, b.w, acc[0][3]);
            acc[1][0] = fmaf(a.y, b.x, acc[1][0]); acc[1][1] = fmaf(a.y, b.y, acc[1][1]);
            acc[1][2] = fmaf(a.y, b.z, acc[1][2]); acc[1][3] = fmaf(a.y, b.w, acc[1][3]);
            acc[2][0] = fmaf(a.z, b.x, acc[2][0]); acc[2][1] = fmaf(a.z, b.y, acc[2][1]);
            acc[2][2] = fmaf(a.z, b.z, acc[2][2]); acc[2][3] = fmaf(a.z, b.w, acc[2][3]);
            acc[3][0] = fmaf(a.w, b.x, acc[3][0]); acc[3][1] = fmaf(a.w, b.y, acc[3][1]);
            acc[3][2] = fmaf(a.w, b.z, acc[3][2]); acc[3][3] = fmaf(a.w, b.w, acc[3][3]);
        }
    }

    if (is_enc) {
        const int b  = m0 >> 9;                  // 512 enc rows per batch
        const int ib = (m0 & 511) + ty * 4;      // i base
        const int hq = (n0 >> 2) + tx;           // h-quad
        float* dst = W4 + (((size_t)b * 64 + hq) * TE + ib) * 4;
        #pragma unroll
        for (int r = 0; r < 4; r++) {
            float4 v;
            v.x = EXP2F(acc[r][0] * KSCALE); v.y = EXP2F(acc[r][1] * KSCALE);
            v.z = EXP2F(acc[r][2] * KSCALE); v.w = EXP2F(acc[r][3] * KSCALE);
            *(float4*)(dst + (size_t)r * 4) = v;
        }
    } else {
        #pragma unroll
        for (int r = 0; r < 4; r++) {
            float4 v;
            v.x = EXP2F(acc[r][0] * KSCALE); v.y = EXP2F(acc[r][1] * KSCALE);
            v.z = EXP2F(acc[r][2] * KSCALE); v.w = EXP2F(acc[r][3] * KSCALE);
            *(float4*)(Uhe + (size_t)(m0 + ty * 4 + r) * HH + n0 + tx * 4) = v;
        }
    }
}

// ---------------------------------------------------------------------------
// k_attn: 512 threads = 8 waves; block owns 4 consecutive j's of ONE batch,
// batch = blockIdx&7 (XCD-local). Phase A: wave w -> i = 64w+lane, 64 h-quads;
// per quad: one b128 W4 load + uniform u/va loads; per j: 4-way batched
// reciprocal (14 fma/mul + 1 rcp per 4 elements). Softmax: waves 0-3.
// Phase B: wave w -> i in [64w,64w+64), all 4 j; 32 KB LDS reduce.
// ---------------------------------------------------------------------------
__global__ __launch_bounds__(512) void k_attn(
    const float* __restrict__ enc, const float* __restrict__ W4,
    const float* __restrict__ Uhe, const float* __restrict__ Va,
    float* __restrict__ out_c, float* __restrict__ out_e)
{
    const int wv = threadIdx.x >> 6, lane = threadIdx.x & 63;
    const int b   = blockIdx.x & 7;           // XCD-local batch
    const int j0  = (blockIdx.x >> 3) * 4;    // 64 j-groups per batch
    const int jj0 = b * TD + j0;              // block-uniform

    __shared__ float sP[4][TE];      // 8 KB: energies -> probabilities
    __shared__ float sR[8][4][HH];   // 32 KB: phase-B partials

    const int i = (wv << 6) + lane;
    const float* wp = W4 + ((size_t)b * 64 * TE + i) * 4;
    const float* ua = Uhe + (size_t)jj0 * HH;   // block-uniform -> s_load
    const float* va = Va;                        // uniform

    float a0 = 0.f, a1 = 0.f, a2 = 0.f, a3 = 0.f;

    // 4-way batched reciprocal:
    //   sum_k v_k/A_k = (nAB*dCD + nCD*dAB) / (dAB*dCD),
    //   A=1+wx*ux.., dAB=A*B, nAB=vx*B+vy*A, ...
#define QSTEP(ACC, U)                                                     \
    {                                                                     \
        float A_ = fmaf(w4.x, (U).x, 1.f);                                \
        float B_ = fmaf(w4.y, (U).y, 1.f);                                \
        float C_ = fmaf(w4.z, (U).z, 1.f);                                \
        float D_ = fmaf(w4.w, (U).w, 1.f);                                \
        float dAB = A_ * B_, dCD = C_ * D_;                               \
        float nAB = fmaf(v4.x, B_, v4.y * A_);                            \
        float nCD = fmaf(v4.z, D_, v4.w * C_);                            \
        float num = fmaf(nAB, dCD, nCD * dAB);                            \
        ACC = fmaf(num, RCPF(dAB * dCD), ACC);                            \
    }

    #pragma unroll 2
    for (int q = 0; q < 64; q++) {
        float4 w4 = *(const float4*)(wp + (size_t)q * TE * 4);
        float4 v4 = *(const float4*)(va + 4 * q);
        float4 u0 = *(const float4*)(ua + 4 * q);
        float4 u1 = *(const float4*)(ua + HH + 4 * q);
        float4 u2 = *(const float4*)(ua + 2 * HH + 4 * q);
        float4 u3 = *(const float4*)(ua + 3 * HH + 4 * q);
        QSTEP(a0, u0)
        QSTEP(a1, u1)
        QSTEP(a2, u2)
        QSTEP(a3, u3)
    }
#undef QSTEP

    // conflict-free b32 writes (lane-stride 4B), energies in log2 domain
    sP[0][i] = NSC * a0;
    sP[1][i] = NSC * a1;
    sP[2][i] = NSC * a2;
    sP[3][i] = NSC * a3;
    __syncthreads();

    // ---- softmax: wave w in 0..3 handles j0+w ----------------------------
    if (wv < 4) {
        float ev[8];
        float m = -3.0e38f;
        #pragma unroll
        for (int k = 0; k < 8; k++) {
            ev[k] = sP[wv][lane + 64 * k];
            m = fmaxf(m, ev[k]);
        }
        #pragma unroll
        for (int off = 32; off; off >>= 1) m = fmaxf(m, __shfl_xor(m, off, 64));
        float s = 0.f;
        #pragma unroll
        for (int k = 0; k < 8; k++) { ev[k] = EXP2F(ev[k] - m); s += ev[k]; }
        #pragma unroll
        for (int off = 32; off; off >>= 1) s += __shfl_xor(s, off, 64);
        float rs = RCPF(s);
        float* oe = out_e + (size_t)(jj0 + wv) * TE;
        #pragma unroll
        for (int k = 0; k < 8; k++) {
            float p = ev[k] * rs;
            sP[wv][lane + 64 * k] = p;
            oe[lane + 64 * k] = p;
        }
    }
    __syncthreads();

    // ---- Phase B: wave w -> i in [64w, 64w+64), all 4 j ------------------
    const int ib = wv << 6;
    const float* eb = enc + ((size_t)b * TE + ib) * HH + 4 * lane;
    float4 c0 = {0,0,0,0}, c1 = {0,0,0,0}, c2 = {0,0,0,0}, c3 = {0,0,0,0};
    #pragma unroll 2
    for (int k = 0; k < 64; k++) {
        float p0 = sP[0][ib + k];   // uniform broadcasts
        float p1 = sP[1][ib + k];
        float p2 = sP[2][ib + k];
        float p3 = sP[3][ib + k];
        float4 q = *(const float4*)(eb + (size_t)k * HH);
        c0.x = fmaf(p0, q.x, c0.x); c0.y = fmaf(p0, q.y, c0.y);
        c0.z = fmaf(p0, q.z, c0.z); c0.w = fmaf(p0, q.w, c0.w);
        c1.x = fmaf(p1, q.x, c1.x); c1.y = fmaf(p1, q.y, c1.y);
        c1.z = fmaf(p1, q.z, c1.z); c1.w = fmaf(p1, q.w, c1.w);
        c2.x = fmaf(p2, q.x, c2.x); c2.y = fmaf(p2, q.y, c2.y);
        c2.z = fmaf(p2, q.z, c2.z); c2.w = fmaf(p2, q.w, c2.w);
        c3.x = fmaf(p3, q.x, c3.x); c3.y = fmaf(p3, q.y, c3.y);
        c3.z = fmaf(p3, q.z, c3.z); c3.w = fmaf(p3, q.w, c3.w);
    }
    *(float4*)&sR[wv][0][4 * lane] = c0;
    *(float4*)&sR[wv][1][4 * lane] = c1;
    *(float4*)&sR[wv][2][4 * lane] = c2;
    *(float4*)&sR[wv][3][4 * lane] = c3;
    __syncthreads();

    // ---- final reduce: wave w -> (j = w&3, h-half = w>>2) ----------------
    {
        const int jr = wv & 3;
        const int h2 = (wv >> 2) * 128 + 2 * lane;
        float sx = 0.f, sy = 0.f;
        #pragma unroll
        for (int ww = 0; ww < 8; ww++) {
            float2 t = *(const float2*)&sR[ww][jr][h2];
            sx += t.x; sy += t.y;
        }
        float2 o; o.x = sx; o.y = sy;
        *(float2*)(out_c + (size_t)(jj0 + jr) * HH + h2) = o;
    }
}

extern "C" void kernel_launch(void* const* d_in, const int* in_sizes, int n_in,
                              void* d_out, int out_size, void* d_ws, size_t ws_size,
                              hipStream_t stream) {
    const float* enc = (const float*)d_in[0];
    const float* dec = (const float*)d_in[1];
    const float* Wa  = (const float*)d_in[2];
    const float* Ua  = (const float*)d_in[3];
    const float* Va  = (const float*)d_in[4];

    float* W4  = (float*)d_ws;                       // exp2-domain, interleaved
    float* Uhe = W4 + (size_t)BB * HH * TE;          // exp2-domain, B*TD*H

    float* out_c = (float*)d_out;                    // [B,TD,H]
    float* out_e = out_c + (size_t)BB * TD * HH;     // [B,TD,TE]

    k_pre<<<384, 256, 0, stream>>>(enc, dec, Wa, Ua, W4, Uhe);
    k_attn<<<BB * TD / 4, 512, 0, stream>>>(enc, W4, Uhe, Va, out_c, out_e);
}